// Round 2
// baseline (517.232 us; speedup 1.0000x reference)
//
#include <hip/hip_runtime.h>
#include <hip/hip_bf16.h>

#define NU 200000
#define NI 200000
#define D 128
#define BATCH 4096

typedef __bf16 bf16x8 __attribute__((ext_vector_type(8)));
typedef float f32x4 __attribute__((ext_vector_type(4)));
struct f8 { f32x4 lo, hi; };

__device__ __forceinline__ f8 ld8(const float* p) {
    f8 r; r.lo = *(const f32x4*)p; r.hi = *(const f32x4*)(p + 4); return r;
}

__device__ __forceinline__ bf16x8 cvt8(f8 v) {
    union { __hip_bfloat16 h[8]; bf16x8 b; } u;
    u.h[0] = __float2bfloat16(v.lo.x); u.h[1] = __float2bfloat16(v.lo.y);
    u.h[2] = __float2bfloat16(v.lo.z); u.h[3] = __float2bfloat16(v.lo.w);
    u.h[4] = __float2bfloat16(v.hi.x); u.h[5] = __float2bfloat16(v.hi.y);
    u.h[6] = __float2bfloat16(v.hi.z); u.h[7] = __float2bfloat16(v.hi.w);
    return u.b;
}

__device__ __forceinline__ void store_bf16x4(__hip_bfloat16* p, float4 v) {
    union { __hip_bfloat16 h[4]; uint2 u; } pk;
    pk.h[0] = __float2bfloat16(v.x);
    pk.h[1] = __float2bfloat16(v.y);
    pk.h[2] = __float2bfloat16(v.z);
    pk.h[3] = __float2bfloat16(v.w);
    *reinterpret_cast<uint2*>(p) = pk.u;
}

__device__ __forceinline__ float4 f4_fma(float s, float4 a, float4 b) {
    return make_float4(fmaf(s, a.x, b.x), fmaf(s, a.y, b.y),
                       fmaf(s, a.z, b.z), fmaf(s, a.w, b.w));
}

// ---------------------------------------------------------------------------
// prep: pred_W -> bf16; combined cell weights [Whh | Wih_emb | Wih_t | pad]
// (128 x 288) bf16; bias sums; last-occurrence argmax per id.
// ---------------------------------------------------------------------------
__global__ __launch_bounds__(256) void prep_kernel(
    const float* __restrict__ predW,
    const float* __restrict__ uWih, const float* __restrict__ uWhh,
    const float* __restrict__ iWih, const float* __restrict__ iWhh,
    const float* __restrict__ ubih, const float* __restrict__ ubhh,
    const float* __restrict__ ibih, const float* __restrict__ ibhh,
    const int* __restrict__ uid, const int* __restrict__ iid,
    __hip_bfloat16* __restrict__ wPred,
    __hip_bfloat16* __restrict__ wU, __hip_bfloat16* __restrict__ wI,
    float* __restrict__ biasU, float* __restrict__ biasI,
    int* __restrict__ lastU, int* __restrict__ lastI)
{
    int idx = blockIdx.x * 256 + threadIdx.x;
    if (idx < 131072) {            // pred_W: 256x512
        wPred[idx] = __float2bfloat16(predW[idx]);
        return;
    }
    idx -= 131072;
    if (idx < 73728) {             // two combined cell weight matrices 128x288
        int z = idx / 36864;
        int r = idx - z * 36864;
        int j = r / 288, k = r - (r / 288) * 288;
        const float* Wih = z ? iWih : uWih;
        const float* Whh = z ? iWhh : uWhh;
        float v = 0.0f;
        if (k < 128)      v = Whh[j * 128 + k];          // h part
        else if (k < 257) v = Wih[j * 129 + (k - 128)];  // x part (emb + time)
        __hip_bfloat16* W = z ? wI : wU;
        W[j * 288 + k] = __float2bfloat16(v);
        return;
    }
    idx -= 73728;
    if (idx < 128) { biasU[idx] = ubih[idx] + ubhh[idx]; return; }
    idx -= 128;
    if (idx < 128) { biasI[idx] = ibih[idx] + ibhh[idx]; return; }
    idx -= 128;
    if (idx < BATCH) { atomicMax(&lastU[uid[idx]], idx); return; }
    idx -= BATCH;
    if (idx < BATCH) { atomicMax(&lastI[iid[idx]], idx); return; }
}

// ---------------------------------------------------------------------------
// Mega kernel: EVERYTHING after prep in one dispatch, no intra-kernel deps.
//   blocks [0,256):    pred-head GEMM, A gathered per-lane into registers
//   blocks [256,512):  RNN-cell GEMMs, A gathered per-lane, scatter epilogue
//   blocks [512,1024): gather-out (o_userEmb / o_itemEmb / o_target)
//   blocks [1024,...): streaming copies (skip scatter-owned rows) + is-select
// A-fragment trick: mfma 16x16x32 A layout means lane (quad,l15) only needs
// cols k0+quad*8 of its row => per lane K/32 bf16x8 chunks built directly
// from the embedding tables (no LDS, no staging pass, no gather->GEMM dep).
// ---------------------------------------------------------------------------
__global__ __launch_bounds__(256) void mega_kernel(
    const int* __restrict__ uid, const int* __restrict__ pid,
    const int* __restrict__ iid,
    const float* __restrict__ t_i, const float* __restrict__ t_u,
    const float* __restrict__ dynU, const float* __restrict__ dynI,
    const float* __restrict__ isU, const float* __restrict__ isI,
    const float* __restrict__ statU, const float* __restrict__ statI,
    const float* __restrict__ initU, const float* __restrict__ initI,
    const float* __restrict__ tdW, const float* __restrict__ tdb,
    const __hip_bfloat16* __restrict__ wPred, const float* __restrict__ predb,
    const __hip_bfloat16* __restrict__ wU, const __hip_bfloat16* __restrict__ wI,
    const float* __restrict__ biasU, const float* __restrict__ biasI,
    const int* __restrict__ lastU, const int* __restrict__ lastI,
    float* __restrict__ o_pred,
    float* __restrict__ o_updU, float* __restrict__ o_updI,
    float* __restrict__ o_userEmb, float* __restrict__ o_itemEmb,
    float* __restrict__ o_target,
    float* __restrict__ o_dynU, float* __restrict__ o_dynI,
    float* __restrict__ o_isU, float* __restrict__ o_isI)
{
    int bx = blockIdx.x;
    int tid = threadIdx.x;

    if (bx >= 1024) {
        // ---- streaming copies (plain loads/stores; skip scatter-owned rows)
        int idx = (bx - 1024) * 256 + tid;
        if (idx < 6400000) {                 // dynU: 200000 x 32 float4
            if (lastU[idx >> 5] < 0)
                ((float4*)o_dynU)[idx] = ((const float4*)dynU)[idx];
            return;
        }
        idx -= 6400000;
        if (idx < 6400000) {                 // dynI
            if (lastI[idx >> 5] < 0)
                ((float4*)o_dynI)[idx] = ((const float4*)dynI)[idx];
            return;
        }
        idx -= 6400000;
        if (idx < 50000) {                   // is_user_new: select final value
            int4 l = ((const int4*)lastU)[idx];
            float4 v = ((const float4*)isU)[idx];
            ((float4*)o_isU)[idx] = make_float4(l.x >= 0 ? 0.0f : v.x,
                                                l.y >= 0 ? 0.0f : v.y,
                                                l.z >= 0 ? 0.0f : v.z,
                                                l.w >= 0 ? 0.0f : v.w);
            return;
        }
        idx -= 50000;
        if (idx < 50000) {                   // is_item_new
            int4 l = ((const int4*)lastI)[idx];
            float4 v = ((const float4*)isI)[idx];
            ((float4*)o_isI)[idx] = make_float4(l.x >= 0 ? 0.0f : v.x,
                                                l.y >= 0 ? 0.0f : v.y,
                                                l.z >= 0 ? 0.0f : v.z,
                                                l.w >= 0 ? 0.0f : v.w);
            return;
        }
        return;
    }

    if (bx >= 512) {
        // ---- gather-out: o_userEmb / o_itemEmb / o_target ----
        int idx = (bx - 512) * 256 + tid;    // < 131072 = 4096 rows x 32 lanes
        int b = idx >> 5, g = idx & 31;
        const float4* dU4 = (const float4*)dynU;
        const float4* dI4 = (const float4*)dynI;
        const float4* sI4 = (const float4*)statI;
        int u = uid[b], i = iid[b];
        float fu = isU[u], fi = isI[i];
        float4 iu = ((const float4*)initU)[g];
        float4 ii = ((const float4*)initI)[g];
        float4 ue = f4_fma(fu, iu, dU4[(size_t)u * 32 + g]);
        float4 ie = f4_fma(fi, ii, dI4[(size_t)i * 32 + g]);
        float4 si = sI4[(size_t)i * 32 + g];
        ((float4*)o_userEmb)[(size_t)b * 32 + g] = ue;
        ((float4*)o_itemEmb)[(size_t)b * 32 + g] = ie;
        ((float4*)o_target)[(size_t)b * 64 + g] = ie;
        ((float4*)o_target)[(size_t)b * 64 + 32 + g] = si;
        return;
    }

    int wave = tid >> 6, lane = tid & 63, quad = lane >> 4, l15 = lane & 15;

    if (bx < 256) {
        // ---- prediction head: A row = [proj | prev_emb | prev_stat | statU]
        int m0 = (bx & 63) * 64, n0 = (bx >> 6) * 64;
        int rowb = m0 + wave * 16 + l15;
        int u = uid[rowb], p = pid[rowb];
        float fu = isU[u], fp = isI[p], ti = t_i[rowb];

        bf16x8 afr[16];
#pragma unroll
        for (int kk = 0; kk < 16; ++kk) {
            int off = (kk & 3) * 32 + quad * 8;   // seg = kk>>2 (quad-indep)
            f8 x;
            if ((kk >> 2) == 0) {
                f8 du = ld8(dynU + (size_t)u * 128 + off);
                f8 iu = ld8(initU + off);
                f8 tw = ld8(tdW + off);
                f8 tb = ld8(tdb + off);
                x.lo = (fu * iu.lo + du.lo) * (1.0f + (ti * tw.lo + tb.lo));
                x.hi = (fu * iu.hi + du.hi) * (1.0f + (ti * tw.hi + tb.hi));
            } else if ((kk >> 2) == 1) {
                f8 dp = ld8(dynI + (size_t)p * 128 + off);
                f8 ii = ld8(initI + off);
                x.lo = fp * ii.lo + dp.lo;
                x.hi = fp * ii.hi + dp.hi;
            } else if ((kk >> 2) == 2) {
                x = ld8(statI + (size_t)p * 128 + off);
            } else {
                x = ld8(statU + (size_t)u * 128 + off);
            }
            afr[kk] = cvt8(x);
        }

        const int K = 512;
        f32x4 acc[4] = {};
#pragma unroll
        for (int kk = 0; kk < 16; ++kk) {
            int k0 = kk * 32;
#pragma unroll
            for (int ct = 0; ct < 4; ++ct) {
                bf16x8 b = *reinterpret_cast<const bf16x8*>(
                    wPred + (size_t)(n0 + ct * 16 + l15) * K + k0 + quad * 8);
                acc[ct] = __builtin_amdgcn_mfma_f32_16x16x32_bf16(afr[kk], b, acc[ct], 0, 0, 0);
            }
        }
        int orow = m0 + wave * 16 + quad * 4;
#pragma unroll
        for (int ct = 0; ct < 4; ++ct) {
            int col = n0 + ct * 16 + l15;
            float bc = predb[col];
#pragma unroll
            for (int r = 0; r < 4; ++r)
                o_pred[(size_t)(orow + r) * 256 + col] = acc[ct][r] + bc;
        }
    } else {
        // ---- RNN cells: A row = [h(128) | x(128) | t | 0 pad] ----
        int bz = bx - 256;
        int z = bz >> 7; bz &= 127;
        int m0 = (bz & 63) * 64, n0 = (bz >> 6) * 64;
        const __hip_bfloat16* W = z ? wI : wU;
        const float* bias = z ? biasI : biasU;
        const int* ids  = z ? iid : uid;
        const int* last = z ? lastI : lastU;
        float* outB = z ? o_updI : o_updU;
        float* outD = z ? o_dynI : o_dynU;

        int rowb = m0 + wave * 16 + l15;
        int u = uid[rowb], i = iid[rowb];
        float fu = isU[u], fi = isI[i];
        float tt = z ? t_u[rowb] : t_i[rowb];

        bf16x8 afr[9];
#pragma unroll
        for (int kk = 0; kk < 9; ++kk) {
            int off = (kk & 3) * 32 + quad * 8;
            f8 x;
            if (kk < 8) {
                // kk<4: h part; kk>=4: x part. user cell(z=0): h=ue,x=ie.
                bool want_ue = (kk < 4) ^ (z != 0);
                if (want_ue) {
                    f8 du = ld8(dynU + (size_t)u * 128 + off);
                    f8 iu = ld8(initU + off);
                    x.lo = fu * iu.lo + du.lo;
                    x.hi = fu * iu.hi + du.hi;
                } else {
                    f8 di = ld8(dynI + (size_t)i * 128 + off);
                    f8 ii = ld8(initI + off);
                    x.lo = fi * ii.lo + di.lo;
                    x.hi = fi * ii.hi + di.hi;
                }
            } else {
                x.lo = 0.0f; x.hi = 0.0f;
                if (quad == 0) x.lo.x = tt;   // col 256 = time, rest pad
            }
            afr[kk] = cvt8(x);
        }

        const int K = 288;
        f32x4 acc[4] = {};
#pragma unroll
        for (int kk = 0; kk < 9; ++kk) {
            int k0 = kk * 32;
#pragma unroll
            for (int ct = 0; ct < 4; ++ct) {
                bf16x8 b = *reinterpret_cast<const bf16x8*>(
                    W + (size_t)(n0 + ct * 16 + l15) * K + k0 + quad * 8);
                acc[ct] = __builtin_amdgcn_mfma_f32_16x16x32_bf16(afr[kk], b, acc[ct], 0, 0, 0);
            }
        }
        int orow = m0 + wave * 16 + quad * 4;
        int rid[4], win[4];
#pragma unroll
        for (int r = 0; r < 4; ++r) {
            int row = orow + r;
            rid[r] = ids[row];
            win[r] = (last[rid[r]] == row);
        }
#pragma unroll
        for (int ct = 0; ct < 4; ++ct) {
            int col = n0 + ct * 16 + l15;
            float bc = bias[col];
#pragma unroll
            for (int r = 0; r < 4; ++r) {
                float v = tanhf(acc[ct][r] + bc);
                outB[(size_t)(orow + r) * D + col] = v;
                if (win[r]) outD[(size_t)rid[r] * D + col] = v;
            }
        }
    }
}

// ---------------------------------------------------------------------------
extern "C" void kernel_launch(void* const* d_in, const int* in_sizes, int n_in,
                              void* d_out, int out_size, void* d_ws, size_t ws_size,
                              hipStream_t stream) {
    const int*   uid   = (const int*)d_in[0];
    const int*   pid   = (const int*)d_in[1];
    const int*   iid   = (const int*)d_in[2];
    const float* t_i   = (const float*)d_in[3];
    const float* t_u   = (const float*)d_in[4];
    const float* dynU  = (const float*)d_in[5];
    const float* dynI  = (const float*)d_in[6];
    const float* isU   = (const float*)d_in[7];
    const float* isI   = (const float*)d_in[8];
    const float* statU = (const float*)d_in[9];
    const float* statI = (const float*)d_in[10];
    const float* initU = (const float*)d_in[11];
    const float* initI = (const float*)d_in[12];
    const float* uWih  = (const float*)d_in[13];
    const float* uWhh  = (const float*)d_in[14];
    const float* ubih  = (const float*)d_in[15];
    const float* ubhh  = (const float*)d_in[16];
    const float* iWih  = (const float*)d_in[17];
    const float* iWhh  = (const float*)d_in[18];
    const float* ibih  = (const float*)d_in[19];
    const float* ibhh  = (const float*)d_in[20];
    const float* predW = (const float*)d_in[21];
    const float* predb = (const float*)d_in[22];
    const float* tdW   = (const float*)d_in[23];
    const float* tdb   = (const float*)d_in[24];

    float* out = (float*)d_out;
    float* o_pred     = out;                 // 4096*256
    float* o_target   = out + 1048576;       // 4096*256
    float* o_updU     = out + 2097152;       // 4096*128
    float* o_userEmb  = out + 2621440;       // 4096*128
    float* o_updI     = out + 3145728;       // 4096*128
    float* o_itemEmb  = out + 3670016;       // 4096*128
    float* o_dynU     = out + 4194304;       // 200000*128
    float* o_dynI     = out + 29794304;      // 200000*128
    float* o_isU      = out + 55394304;      // 200000
    float* o_isI      = out + 55594304;      // 200000

    char* ws = (char*)d_ws;
    int* lastU = (int*)ws;                               // NU ints
    int* lastI = lastU + NU;                             // NI ints
    __hip_bfloat16* wPred = (__hip_bfloat16*)(ws + 10512896);    // 256*512 bf16
    __hip_bfloat16* wU    = (__hip_bfloat16*)(ws + 10775040);    // 128*288 bf16
    __hip_bfloat16* wI    = (__hip_bfloat16*)(ws + 10848768);    // 128*288 bf16
    float* biasU = (float*)(ws + 10922496);                      // 128 f32
    float* biasI = (float*)(ws + 10923008);                      // 128 f32

    // 1. last-writer arrays := -1
    hipMemsetAsync(lastU, 0xFF, (size_t)(NU + NI) * sizeof(int), stream);

    // 2. weight conversion + bias sums + last-occurrence argmax (213248 thr)
    prep_kernel<<<833, 256, 0, stream>>>(
        predW, uWih, uWhh, iWih, iWhh, ubih, ubhh, ibih, ibhh,
        uid, iid, wPred, wU, wI, biasU, biasI, lastU, lastI);

    // 3. everything else in one dispatch:
    //    512 GEMM + 512 gather-out + 25000+25000+391 copy = 51415 blocks
    mega_kernel<<<51415, 256, 0, stream>>>(
        uid, pid, iid, t_i, t_u, dynU, dynI, isU, isI, statU, statI,
        initU, initI, tdW, tdb,
        wPred, predb, wU, wI, biasU, biasI, lastU, lastI,
        o_pred, o_updU, o_updI, o_userEmb, o_itemEmb, o_target,
        o_dynU, o_dynI, o_isU, o_isI);
}